// Round 10
// baseline (97.075 us; speedup 1.0000x reference)
//
#include <hip/hip_runtime.h>
#include <hip/hip_bf16.h>
#include <stdint.h>

typedef __attribute__((ext_vector_type(8))) short short8;
typedef __attribute__((ext_vector_type(8))) unsigned short ushort8;
typedef __attribute__((ext_vector_type(4))) float f32x4;
typedef __attribute__((ext_vector_type(4))) int int4v;

#define NHEAD 32
#define SEQ   2048
#define HN    128

static constexpr float INV_NORM = 0.08838834764831845f;  // 1/sqrt(128), folded into Q

__device__ __forceinline__ unsigned short f2bf(float f) {
  union { float f; unsigned u; } v; v.f = f;
  unsigned r = v.u + 0x7fffu + ((v.u >> 16) & 1u);   // RNE
  return (unsigned short)(r >> 16);
}

__device__ __forceinline__ f32x4 mfma16(short8 a, short8 b, f32x4 c) {
  return __builtin_amdgcn_mfma_f32_16x16x32_bf16(a, b, c, 0, 0, 0);
}

__device__ __forceinline__ void gl_lds16(const void* g, void* l) {
  __builtin_amdgcn_global_load_lds(
      (const __attribute__((address_space(1))) unsigned int*)g,
      (__attribute__((address_space(3))) unsigned int*)l, 16, 0, 0);
}

// ---- fused prep: K -> kswz (XOR-swizzled rows, R0-R7 proven, for LDS
// staging); V -> vfr (per-32kv-tile FRAGMENT layout, R8-proven: main
// kernel reads V fragments as coalesced 1KB global loads, no LDS).
__global__ __launch_bounds__(256) void prep_kv(const float* __restrict__ K,
                                               const float* __restrict__ V,
                                               unsigned short* __restrict__ kswz,
                                               unsigned short* __restrict__ vfr) {
  __shared__ unsigned short lds[128 * 136];
  int bid = blockIdx.x;
  int tid = threadIdx.x;
  if (bid < 4096) {
    int idx = bid * 256 + tid;     // chunk id: 32*2048*16
    int cl = idx & 15;
    int t  = (idx >> 4) & 2047;
    int bn = idx >> 15;
    const float4* src = (const float4*)(K + ((size_t)t * 32 + bn) * 128 + cl * 8);
    float4 a = src[0], b = src[1];
    ushort8 o;
    o[0]=f2bf(a.x); o[1]=f2bf(a.y); o[2]=f2bf(a.z); o[3]=f2bf(a.w);
    o[4]=f2bf(b.x); o[5]=f2bf(b.y); o[6]=f2bf(b.z); o[7]=f2bf(b.w);
    *(ushort8*)(kswz + ((size_t)bn * 2048 + t) * 128 + ((cl ^ (t & 7)) * 8)) = o;
  } else {
    int vb = bid - 4096;
    int bn = vb >> 4;
    int t0 = (vb & 15) << 7;
    int r = tid >> 1, h0 = (tid & 1) * 64;
    const float* src = V + ((size_t)(t0 + r) * 32 + bn) * 128 + h0;
#pragma unroll
    for (int j = 0; j < 8; ++j) {
      float4 a = *(const float4*)(src + j * 8);
      float4 b = *(const float4*)(src + j * 8 + 4);
      ushort8 o;
      o[0]=f2bf(a.x); o[1]=f2bf(a.y); o[2]=f2bf(a.z); o[3]=f2bf(a.w);
      o[4]=f2bf(b.x); o[5]=f2bf(b.y); o[6]=f2bf(b.z); o[7]=f2bf(b.w);
      *(ushort8*)&lds[r * 136 + h0 + j * 8] = o;
    }
    __syncthreads();
    int h = tid >> 1, ts = (tid & 1) * 64;
    unsigned short tmp[64];
#pragma unroll
    for (int j = 0; j < 64; ++j) {
      int p = j & 31;
      int tloc = ((p >> 3) & 3) * 4 + ((p >> 2) & 1) * 16 + (p & 3);
      tmp[j] = lds[(ts + (j & 32) + tloc) * 136 + h];
    }
    // scatter 8-col groups into per-tile fragment layout (R8-proven)
#pragma unroll
    for (int j = 0; j < 8; ++j) {
      int c0 = t0 + ts + j * 8;          // column base (mult of 8)
      int tg = c0 >> 5;                  // 32-kv tile
      int hv = (c0 >> 3) & 3;            // hi group within tile
      size_t du = (size_t)bn * 32768 + (size_t)tg * 512 +
                  (h >> 4) * 64 + hv * 16 + (h & 15);
      *(ushort8*)(vfr + du * 8) = *(ushort8*)&tmp[j * 8];
    }
  }
}

// ---- fragment/softmax helpers --------------------------------------------
__device__ __forceinline__ void read_kf(const char* kb, int l15, int hi,
                                        short8 (&kf)[2][4]) {
  int xr = (l15 & 7) << 4;      // rows nt*16+l15: (row&7)==(l15&7), xr invariant
#pragma unroll
  for (int nt = 0; nt < 2; ++nt) {
    const char* krow = kb + (nt * 16 + l15) * 256;
#pragma unroll
    for (int kk = 0; kk < 4; ++kk)
      kf[nt][kk] = *(const short8*)(krow + (((kk * 4 + hi) * 16) ^ xr));
  }
}

__device__ __forceinline__ short8 packp(const float (&e)[8], float& da) {
  da += ((e[0] + e[1]) + (e[2] + e[3])) + ((e[4] + e[5]) + (e[6] + e[7]));
  unsigned w0, w1, w2, w3;
  asm("v_cvt_pk_bf16_f32 %0, %1, %2" : "=v"(w0) : "v"(e[0]), "v"(e[1]));
  asm("v_cvt_pk_bf16_f32 %0, %1, %2" : "=v"(w1) : "v"(e[2]), "v"(e[3]));
  asm("v_cvt_pk_bf16_f32 %0, %1, %2" : "=v"(w2) : "v"(e[4]), "v"(e[5]));
  asm("v_cvt_pk_bf16_f32 %0, %1, %2" : "=v"(w3) : "v"(e[6]), "v"(e[7]));
  union { int4v u; short8 s; } pk;
  pk.u = (int4v){(int)w0, (int)w1, (int)w2, (int)w3};
  return pk.s;
}

// Q pre-scaled by 1/sqrt(128): probability = exp(S) directly.
__device__ __forceinline__ short8 softp_m(const f32x4 (&sv)[2], int t0h, int qbase,
                                          int l15, int hi, float& da) {
  float e[8];
#pragma unroll
  for (int nt = 0; nt < 2; ++nt)
#pragma unroll
    for (int i = 0; i < 4; ++i) {
      float x = __expf(sv[nt][i]);
      int kv = t0h + nt * 16 + hi * 4 + i;
      e[nt * 4 + i] = (kv <= qbase + l15) ? x : 0.0f;
    }
  return packp(e, da);
}

__device__ __forceinline__ short8 softp_u(const f32x4 (&sv)[2], float& da) {
  float e[8];
#pragma unroll
  for (int nt = 0; nt < 2; ++nt)
#pragma unroll
    for (int i = 0; i < 4; ++i)
      e[nt * 4 + i] = __expf(sv[nt][i]);
  return packp(e, da);
}

// ---- main: R7 structure (the champion: 512 blocks x 512 threads, 8
// waves x 16 q-rows = 128-row q-tile, KVB=64, lockstep barrier/64kv,
// pair-balanced {z,z+8} qt sums 15) with ONE change: V comes straight
// from global vfr fragments (R8-proven layout), never through LDS.
// R7 model: 288KB LDS-port bytes per block-iter -> ~44us of the 55.5us
// wall was LDS.  Now: stage K 16KB + kf reads 8x16KB = 144KB/iter ->
// LDS floor ~22us.  V loads (1KB coalesced, L1-shared by 8 waves,
// XCD-pinned heads keep K+V in the 4MB L2) issue right after kf
// ds_reads; ~200cyc L2 latency hides under QKT+softmax + 4 waves/SIMD.
// __launch_bounds__(512,2): reg cap 128 (cap=256/w, R1/R3).
__global__ __launch_bounds__(512, 2) void attn_main(const float* __restrict__ Q,
                                                    const unsigned short* __restrict__ kswz,
                                                    const unsigned short* __restrict__ vfr,
                                                    float* __restrict__ out) {
  // LDS: K only, double-buffered: 2 x 16KB = 32768
  __shared__ char smem[32768];
  int tid = threadIdx.x;
  int lane = tid & 63;
  int w = tid >> 6;                     // 0..7
  int l15 = lane & 15;
  int hi = lane >> 4;

  int bid = blockIdx.x;
  int bn = bid & 31;                    // head -> XCD bid%8 = bn%8 (stable)
  int z = bid >> 5;                     // [0,16)
  int qt = (z < 8) ? (15 - z) : (z - 8);
  int qb = qt * 128 + w * 16;           // this wave's 16 q-rows
  int ntile = 2 * qt + 2;               // 64-kv iterations

  // Q B-fragments, PRE-SCALED by 1/sqrt(128): softmax is exp(S) direct.
  short8 qf[4];
  {
    const float* qrow = Q + ((size_t)(qb + l15) * 32 + bn) * 128;
#pragma unroll
    for (int kk = 0; kk < 4; ++kk) {
      float4 a = *(const float4*)(qrow + kk * 32 + hi * 8);
      float4 b = *(const float4*)(qrow + kk * 32 + hi * 8 + 4);
      short8 o;
      o[0]=(short)f2bf(a.x*INV_NORM); o[1]=(short)f2bf(a.y*INV_NORM);
      o[2]=(short)f2bf(a.z*INV_NORM); o[3]=(short)f2bf(a.w*INV_NORM);
      o[4]=(short)f2bf(b.x*INV_NORM); o[5]=(short)f2bf(b.y*INV_NORM);
      o[6]=(short)f2bf(b.z*INV_NORM); o[7]=(short)f2bf(b.w*INV_NORM);
      qf[kk] = o;
    }
  }

  f32x4 zz = {0.f, 0.f, 0.f, 0.f};
  f32x4 acc[8];
#pragma unroll
  for (int ht = 0; ht < 8; ++ht) acc[ht] = zz;
  float dacc = 0.f;

  const char* kg = (const char*)(kswz + (size_t)bn * 2048 * 128);
  const char* vg = (const char*)vfr + (size_t)bn * 524288;   // 64 tiles x 8KB

  auto stage = [&](int buf, int t0) {  // K only: 2 gl_lds per lane (16KB)
    const char* ksrc = kg + (size_t)t0 * 256;
    char* kl = smem + buf * 16384;
#pragma unroll
    for (int rr = 0; rr < 2; ++rr)
      gl_lds16(ksrc + (size_t)(tid + rr * 512) * 16, kl + (tid + rr * 512) * 16);
  };

  // drain Q loads so in-loop vmcnt sees ONLY stage loads
  asm volatile("s_waitcnt vmcnt(0)" ::: "memory");
  stage(0, 0);

  int cur = 0;
  for (int it = 0; it < ntile; ++it) {
    int t0 = it * 64;
    asm volatile("s_waitcnt vmcnt(0)" ::: "memory");   // stage(it) landed
    __builtin_amdgcn_s_barrier();                      // all waves' stage done
    if (it + 1 < ntile) stage(cur ^ 1, t0 + 64);       // prefetch next K tile

    const char* kb = smem + cur * 16384;
#pragma unroll
    for (int half = 0; half < 2; ++half) {
      int t0h = t0 + half * 32;
      if (t0h <= qb + 15) {
        const char* kbh = kb + half * 8192;
        const char* vbg = vg + (size_t)(it * 2 + half) * 8192;
        // K fragments from LDS
        short8 kf[2][4];
        read_kf(kbh, l15, hi, kf);
        // V fragments: 8 coalesced 1KB global loads, issued NOW so the
        // L2 latency hides under QKT + softmax (consumed only at PV)
        short8 vf[8];
#pragma unroll
        for (int ht = 0; ht < 8; ++ht)
          vf[ht] = *(const short8*)(vbg + ht * 1024 + lane * 16);
        // QK^T (swapped): lane holds S^T[kv = 4hi+i (+16nt)][q = l15]
        f32x4 sv[2] = {zz, zz};
        __builtin_amdgcn_s_setprio(1);
#pragma unroll
        for (int nt = 0; nt < 2; ++nt)
#pragma unroll
          for (int kk = 0; kk < 4; ++kk)
            sv[nt] = mfma16(kf[nt][kk], qf[kk], sv[nt]);
        __builtin_amdgcn_s_setprio(0);
        bool mask = (t0h + 31 > qb);
        short8 p = mask ? softp_m(sv, t0h, qb, l15, hi, dacc)
                        : softp_u(sv, dacc);
        // PV (V rows pre-permuted to match P k-slot order)
        __builtin_amdgcn_s_setprio(1);
#pragma unroll
        for (int ht = 0; ht < 8; ++ht)
          acc[ht] = mfma16(p, vf[ht], acc[ht]);
        __builtin_amdgcn_s_setprio(0);
      }
    }
    cur ^= 1;
  }

  // denominator: reduce partials across hi (lanes l15 + 16*hi)
  {
    float d = dacc;
    d += __shfl_xor(d, 16);
    d += __shfl_xor(d, 32);
    dacc = d;                        // function of l15 only
  }
  float* dn = out + 8388608;
  if (hi == 0) dn[(size_t)bn * 2048 + qb + l15] = dacc;

  // per-output-row inverse denominators via lane broadcast
  float inv[4];
#pragma unroll
  for (int i = 0; i < 4; ++i)
    inv[i] = __builtin_amdgcn_rcpf(__shfl(dacc, hi * 4 + i));

  // ctx: out[s*4096 + bn*128 + h]; lane holds O[q = qb+4hi+i][h = 16ht+l15]
#pragma unroll
  for (int i = 0; i < 4; ++i) {
    float* orow = out + (size_t)(qb + hi * 4 + i) * 4096 + bn * 128 + l15;
#pragma unroll
    for (int ht = 0; ht < 8; ++ht)
      orow[ht * 16] = acc[ht][i] * inv[i];
  }
}

extern "C" void kernel_launch(void* const* d_in, const int* in_sizes, int n_in,
                              void* d_out, int out_size, void* d_ws, size_t ws_size,
                              hipStream_t stream) {
  const float* Q = (const float*)d_in[0];
  const float* K = (const float*)d_in[1];
  const float* V = (const float*)d_in[2];
  float* out = (float*)d_out;

  unsigned short* kswz = (unsigned short*)d_ws;
  unsigned short* vfr  = kswz + (size_t)NHEAD * SEQ * HN;

  prep_kv<<<4608, 256, 0, stream>>>(K, V, kswz, vfr);
  attn_main<<<512, 512, 0, stream>>>(Q, kswz, vfr, out);
}